// Round 3
// baseline (2015.277 us; speedup 1.0000x reference)
//
#include <hip/hip_runtime.h>
#include <stdint.h>

// ---------------------------------------------------------------------------
// Zorro-style multimodal transformer, B=4, N=1040 (512+512+16 fusion), D=1024,
// H=16, DH=64, L=4, FF=2730 gated-GELU; final LN + 4-token masked pool attn.
// bf16 MFMA GEMMs (m97 structure: 128x128 tile, global_load_lds 16B),
// block-mask-aware flash attention (contiguous col ranges per row type).
// R3: (1) XCD-ownership band swizzle in gemm_bt (id%8 -> fixed n-panels),
//     (2) Q+KV merged into one N=3072 GEMM, (3) split-K=2 atomicAdd for the
//     WO and ff2 residual GEMMs. Workspace ~63 MB.
// ---------------------------------------------------------------------------

#define DEV __device__ __forceinline__

typedef unsigned short u16;
typedef __attribute__((ext_vector_type(8))) __bf16 bf16x8;
typedef __attribute__((ext_vector_type(4))) float floatx4;

DEV u16 f2bf(float f) {
  union { float f; unsigned u; } v; v.f = f;
  return (u16)((v.u + 0x7fffu + ((v.u >> 16) & 1u)) >> 16);  // RNE
}
DEV float bf2f(u16 s) {
  union { unsigned u; float f; } v; v.u = ((unsigned)s) << 16;
  return v.f;
}

#define MFMA(a, b, c) __builtin_amdgcn_mfma_f32_16x16x32_bf16(a, b, c, 0, 0, 0)

DEV void gld16(const u16* g, u16* l) {
  __builtin_amdgcn_global_load_lds((__attribute__((address_space(1))) void*)g,
                                   (__attribute__((address_space(3))) void*)l,
                                   16, 0, 0);
}

// ---------------- constants ----------------
#define MREAL 4160   /* B*N = 4*1040 */
#define MPAD  4224   /* 33*128 */
#define NPAD  1056   /* 1040 padded to x32 */
#define FFP   2752   /* 2730 padded */
#define FF2P  5504

// ---------------- weight conversion ----------------
// out[n*Kstride + k] = (k < Kin) ? bf16(in[k*N + n]) : 0    (B^T bf16 layout)
__global__ __launch_bounds__(256) void transpose_cvt(
    const float* __restrict__ in, u16* __restrict__ out,
    int Kin, int N, int Kstride) {
  __shared__ float tile[32][33];
  const int k0 = blockIdx.x * 32, n0 = blockIdx.y * 32;
  const int tx = threadIdx.x, ty = threadIdx.y;
#pragma unroll
  for (int i = 0; i < 4; i++) {
    int k = k0 + ty + i * 8;
    tile[ty + i * 8][tx] = (k < Kin) ? in[(int64_t)k * N + n0 + tx] : 0.f;
  }
  __syncthreads();
#pragma unroll
  for (int i = 0; i < 4; i++) {
    int n = n0 + ty + i * 8;
    int k = k0 + tx;
    if (k < Kstride) out[(int64_t)n * Kstride + k] = f2bf(tile[tx][ty + i * 8]);
  }
}

// ff_w1 [1024 x 5460] -> w1T [5504 x 1024] bf16 with val/gate 16-col interleave:
// out row r: vi = (r/32)*16 + r%16 ; gate if (r/16)&1 ; src col = gate? 2730+vi : vi
__global__ __launch_bounds__(256) void transpose_w1(
    const float* __restrict__ in, u16* __restrict__ out) {
  __shared__ float tile[32][33];
  const int k0 = blockIdx.x * 32;        // D dim
  const int r0 = blockIdx.y * 32;        // output-row dim
  const int tx = threadIdx.x, ty = threadIdx.y;
  const int vb = (r0 >> 5) << 4;         // = r0/2
  const int vi = vb + (tx & 15);
  const int c = (tx < 16) ? vi : 2730 + vi;
  const bool valid = vi < 2730;
#pragma unroll
  for (int i = 0; i < 4; i++) {
    int k = k0 + ty + i * 8;
    tile[ty + i * 8][tx] = valid ? in[(int64_t)k * 5460 + c] : 0.f;
  }
  __syncthreads();
#pragma unroll
  for (int i = 0; i < 4; i++) {
    int rl = ty + i * 8;
    out[(int64_t)(r0 + rl) * 1024 + k0 + tx] = f2bf(tile[tx][rl]);
  }
}

// ---------------- tokens assembly ----------------
__global__ __launch_bounds__(256) void build_tokens_k(
    const float* __restrict__ m0p, const float* __restrict__ m1p,
    const float* __restrict__ fus, float* __restrict__ tokens) {
  const int n = blockIdx.x, b = blockIdx.y, t = threadIdx.x;
  const float* src = (n < 512) ? m0p + ((int64_t)b * 512 + n) * 1024
                   : (n < 1024) ? m1p + ((int64_t)b * 512 + (n - 512)) * 1024
                                : fus + (int64_t)(n - 1024) * 1024;
  float4 v = ((const float4*)src)[t];
  ((float4*)(tokens + ((int64_t)b * 1040 + n) * 1024))[t] = v;
}

// ---------------- layernorm (f32 in, bf16 out) ----------------
__global__ __launch_bounds__(256) void ln_k(const float* __restrict__ x,
                                            const float* __restrict__ gamma,
                                            u16* __restrict__ out) {
  const int r = blockIdx.x, t = threadIdx.x;
  const float4 v = ((const float4*)(x + (int64_t)r * 1024))[t];
  float s = v.x + v.y + v.z + v.w;
  float q = v.x * v.x + v.y * v.y + v.z * v.z + v.w * v.w;
#pragma unroll
  for (int off = 32; off >= 1; off >>= 1) {
    s += __shfl_xor(s, off);
    q += __shfl_xor(q, off);
  }
  __shared__ float red[8];
  const int w = t >> 6, l = t & 63;
  if (l == 0) { red[w] = s; red[4 + w] = q; }
  __syncthreads();
  s = red[0] + red[1] + red[2] + red[3];
  q = red[4] + red[5] + red[6] + red[7];
  const float mu = s * (1.f / 1024.f);
  const float var = q * (1.f / 1024.f) - mu * mu;
  const float rs = rsqrtf(var + 1e-5f);
  const float4 g = ((const float4*)gamma)[t];
  u16* op = out + (int64_t)r * 1024 + t * 4;
  op[0] = f2bf((v.x - mu) * rs * g.x);
  op[1] = f2bf((v.y - mu) * rs * g.y);
  op[2] = f2bf((v.z - mu) * rs * g.z);
  op[3] = f2bf((v.w - mu) * rs * g.w);
}

// ---------------- MFMA GEMM: C[M,N] = A[M,K](bf16) @ Bt[N,K](bf16) ----------------
enum { EPI_QKV = 0, EPI_KV = 1, EPI_TOKADD = 2, EPI_GG = 3 };

// Kstr = row stride of A and Bt; per-z K-range = Kstr / gridDim.z.
template <int EPI>
__global__ __launch_bounds__(256) void gemm_bt(
    const u16* __restrict__ A, const u16* __restrict__ Bt,
    int Kstr, int Mreal,
    float* __restrict__ tokens, u16* __restrict__ oq, u16* __restrict__ ok,
    u16* __restrict__ ovT, u16* __restrict__ oh2) {
  __shared__ __align__(16) u16 lA[128 * 32];
  __shared__ __align__(16) u16 lB[128 * 32];
  const int t = threadIdx.x;
  const int w = t >> 6, l = t & 63;
  const int lane16 = l & 15, quad = l >> 4;

  // XCD-ownership swizzle: bands of 8 n-blocks, m-major inside a band.
  // With round-robin id%8 -> XCD, each XCD owns a fixed set of n-panels.
  const int gx = gridDim.x, gy = gridDim.y;
  const int id = blockIdx.y * gx + blockIdx.x;
  const int bandSz = gy * 8;
  const int band = id / bandSz;
  const int rem = id - band * bandSz;
  const int bw = min(8, gx - band * 8);
  const int mblk = rem / bw;
  const int nblk = band * 8 + rem % bw;
  const int m0 = mblk * 128, n0 = nblk * 128;
  const int wm = (w >> 1) * 64, wn = (w & 1) * 64;

  const int Klen = Kstr / gridDim.z;
  const int koff = blockIdx.z * Klen;

  const floatx4 fz = {0.f, 0.f, 0.f, 0.f};
  floatx4 acc[4][4];
#pragma unroll
  for (int i = 0; i < 4; i++)
#pragma unroll
    for (int j = 0; j < 4; j++) acc[i][j] = fz;

  const int rowL = t >> 2;
  const int colL = (t & 3) * 8;
  const u16* gA = A + (int64_t)(m0 + rowL) * Kstr + koff + colL;
  const u16* gB = Bt + (int64_t)(n0 + rowL) * Kstr + koff + colL;
  u16* lAp = lA + t * 8;
  u16* lBp = lB + t * 8;
  const u16* pa = lA + (wm + lane16) * 32 + quad * 8;
  const u16* pb = lB + (wn + lane16) * 32 + quad * 8;

  for (int kt = 0; kt < Klen; kt += 32) {
    gld16(gA + kt, lAp);
    gld16(gA + kt + (int64_t)64 * Kstr, lAp + 64 * 32);
    gld16(gB + kt, lBp);
    gld16(gB + kt + (int64_t)64 * Kstr, lBp + 64 * 32);
    __syncthreads();
    bf16x8 af[4], bf[4];
#pragma unroll
    for (int i = 0; i < 4; i++) af[i] = *(const bf16x8*)(pa + i * 16 * 32);
#pragma unroll
    for (int j = 0; j < 4; j++) bf[j] = *(const bf16x8*)(pb + j * 16 * 32);
#pragma unroll
    for (int i = 0; i < 4; i++)
#pragma unroll
      for (int j = 0; j < 4; j++) acc[i][j] = MFMA(af[i], bf[j], acc[i][j]);
    __syncthreads();
  }

  // Epilogues. C-layout: lane holds row = quad*4+reg, col = lane16 within frag.
  if constexpr (EPI == EPI_TOKADD) {
    const bool atomic = gridDim.z > 1;
#pragma unroll
    for (int i = 0; i < 4; i++) {
      const int mb = m0 + wm + i * 16 + quad * 4;
#pragma unroll
      for (int reg = 0; reg < 4; reg++) {
        const int m = mb + reg;
        if (m < Mreal) {
          float* tp = tokens + (int64_t)m * 1024;
#pragma unroll
          for (int j = 0; j < 4; j++) {
            const int n = n0 + wn + j * 16 + lane16;
            if (atomic) atomicAdd(tp + n, acc[i][j][reg]);
            else tp[n] += acc[i][j][reg];
          }
        }
      }
    }
  } else if constexpr (EPI == EPI_QKV) {
    // cols [0,1024): Q (scaled), [1024,2048): K, [2048,3072): V^T
#pragma unroll
    for (int i = 0; i < 4; i++) {
      const int mb = m0 + wm + i * 16 + quad * 4;
#pragma unroll
      for (int reg = 0; reg < 4; reg++) {
        const int m = mb + reg;
        if (m < Mreal) {
          const int b = m / 1040, rb = m % 1040;
#pragma unroll
          for (int j = 0; j < 4; j++) {
            const int n = n0 + wn + j * 16 + lane16;
            const float v = acc[i][j][reg];
            if (n < 1024) {
              const int hd = n >> 6, d = n & 63;
              oq[(((int64_t)b * 16 + hd) * NPAD + rb) * 64 + d] = f2bf(v * 0.125f);
            } else if (n < 2048) {
              const int n2 = n - 1024;
              const int hd = n2 >> 6, d = n2 & 63;
              ok[(((int64_t)b * 16 + hd) * NPAD + rb) * 64 + d] = f2bf(v);
            } else {
              const int n2 = n - 2048;
              const int hd = n2 >> 6, d = n2 & 63;
              ovT[(((int64_t)b * 16 + hd) * 64 + d) * NPAD + rb] = f2bf(v);
            }
          }
        }
      }
    }
  } else if constexpr (EPI == EPI_KV) {
#pragma unroll
    for (int i = 0; i < 4; i++) {
      const int mb = m0 + wm + i * 16 + quad * 4;
#pragma unroll
      for (int reg = 0; reg < 4; reg++) {
        const int m = mb + reg;
        if (m < Mreal) {
          const int b = m / 1040, rb = m % 1040;
#pragma unroll
          for (int j = 0; j < 4; j++) {
            const int n = n0 + wn + j * 16 + lane16;
            const float v = acc[i][j][reg];
            if (n < 1024) {
              const int hd = n >> 6, d = n & 63;
              ok[(((int64_t)b * 16 + hd) * NPAD + rb) * 64 + d] = f2bf(v);
            } else {
              const int n2 = n - 1024;
              const int hd = n2 >> 6, d = n2 & 63;
              ovT[(((int64_t)b * 16 + hd) * 64 + d) * NPAD + rb] = f2bf(v);
            }
          }
        }
      }
    }
  } else {  // EPI_GG: cols are (val,gate) alternating 16-groups
#pragma unroll
    for (int i = 0; i < 4; i++) {
      const int mb = m0 + wm + i * 16 + quad * 4;
#pragma unroll
      for (int reg = 0; reg < 4; reg++) {
        const int m = mb + reg;
        u16* hp = oh2 + (int64_t)m * FFP;
#pragma unroll
        for (int j = 0; j < 4; j += 2) {
          const float val = acc[i][j][reg];
          const float g = acc[i][j + 1][reg];
          const float ge = 0.5f * g * (1.f + erff(g * 0.70710678118654752f));
          const int vi = (((n0 + wn + j * 16) >> 5) << 4) + lane16;
          hp[vi] = f2bf(val * ge);
        }
      }
    }
  }
}

// ---------------- block-mask flash attention ----------------
__global__ __launch_bounds__(256) void attn_k(const u16* __restrict__ qb,
                                              const u16* __restrict__ kb,
                                              const u16* __restrict__ vTb,
                                              u16* __restrict__ ao) {
  const int t = threadIdx.x, w = t >> 6, l = t & 63;
  const int lane16 = l & 15, quad = l >> 4;
  const int bh = blockIdx.y, b = bh >> 4, h = bh & 15;
  const int row0 = blockIdx.x * 64 + w * 16;
  __shared__ __align__(16) u16 lp[4][16 * 32];
  if (row0 >= 1040) return;
  u16* myp = lp[w];
  const int type = (row0 < 512) ? 0 : (row0 < 1024 ? 1 : 2);
  const int cbeg = (type == 1) ? 512 : 0;
  const int cend = (type == 0) ? 512 : (type == 1 ? 1024 : 1040);
  const int niter = (cend - cbeg + 31) >> 5;

  const u16* qp = qb + ((int64_t)bh * NPAD + row0 + lane16) * 64 + quad * 8;
  const bf16x8 a0 = *(const bf16x8*)qp;
  const bf16x8 a1 = *(const bf16x8*)(qp + 32);

  const floatx4 fz = {0.f, 0.f, 0.f, 0.f};
  floatx4 O[4] = {fz, fz, fz, fz};
  float mrow[4] = {-1e30f, -1e30f, -1e30f, -1e30f};
  float lrow[4] = {0.f, 0.f, 0.f, 0.f};

  for (int it = 0; it < niter; ++it) {
    const int c0 = cbeg + it * 32;
    const u16* kp = kb + ((int64_t)bh * NPAD + c0 + lane16) * 64 + quad * 8;
    bf16x8 b00 = *(const bf16x8*)kp;
    bf16x8 b01 = *(const bf16x8*)(kp + 32);
    bf16x8 b10 = *(const bf16x8*)(kp + 16 * 64);
    bf16x8 b11 = *(const bf16x8*)(kp + 16 * 64 + 32);
    floatx4 s0 = MFMA(a0, b00, fz); s0 = MFMA(a1, b01, s0);
    floatx4 s1 = MFMA(a0, b10, fz); s1 = MFMA(a1, b11, s1);
    if (c0 + 32 > cend) {  // fusion tail mask (cols >= cend)
      if (c0 + lane16 >= cend) { s0[0] = s0[1] = s0[2] = s0[3] = -1e30f; }
      if (c0 + 16 + lane16 >= cend) { s1[0] = s1[1] = s1[2] = s1[3] = -1e30f; }
    }
    float al[4];
#pragma unroll
    for (int r = 0; r < 4; r++) {
      float tm = fmaxf(s0[r], s1[r]);
      tm = fmaxf(tm, __shfl_xor(tm, 1));
      tm = fmaxf(tm, __shfl_xor(tm, 2));
      tm = fmaxf(tm, __shfl_xor(tm, 4));
      tm = fmaxf(tm, __shfl_xor(tm, 8));
      const float mn = fmaxf(mrow[r], tm);
      const float p0 = __expf(s0[r] - mn);
      const float p1 = __expf(s1[r] - mn);
      float ps = p0 + p1;
      ps += __shfl_xor(ps, 1); ps += __shfl_xor(ps, 2);
      ps += __shfl_xor(ps, 4); ps += __shfl_xor(ps, 8);
      const float a_ = __expf(mrow[r] - mn);
      lrow[r] = lrow[r] * a_ + ps;
      mrow[r] = mn;
      al[r] = a_;
      myp[(quad * 4 + r) * 32 + lane16] = f2bf(p0);
      myp[(quad * 4 + r) * 32 + 16 + lane16] = f2bf(p1);
    }
#pragma unroll
    for (int dt = 0; dt < 4; dt++) {
      O[dt][0] *= al[0]; O[dt][1] *= al[1];
      O[dt][2] *= al[2]; O[dt][3] *= al[3];
    }
    const bf16x8 pf = *(const bf16x8*)(myp + lane16 * 32 + quad * 8);  // A-layout
#pragma unroll
    for (int dt = 0; dt < 4; dt++) {
      const u16* vp = vTb + ((int64_t)bh * 64 + dt * 16 + lane16) * NPAD + c0 + quad * 8;
      const bf16x8 bv = *(const bf16x8*)vp;
      O[dt] = MFMA(pf, bv, O[dt]);
    }
  }
#pragma unroll
  for (int dt = 0; dt < 4; dt++)
#pragma unroll
    for (int r = 0; r < 4; r++) {
      const int row = row0 + quad * 4 + r;
      ao[((int64_t)b * 1040 + row) * 1024 + h * 64 + dt * 16 + lane16] =
          f2bf(O[dt][r] / lrow[r]);
    }
}

// ---------------- pool q: qP[16,1024] = return_tokens @ pool_wq * 0.125 ----------------
__global__ __launch_bounds__(256) void poolq_k(const float* __restrict__ rtk,
                                               const float* __restrict__ pwq,
                                               u16* __restrict__ qP) {
  const int r = blockIdx.y;
  const int n = blockIdx.x * 256 + threadIdx.x;
  const float* x = rtk + (int64_t)r * 1024;
  float acc = 0.f;
#pragma unroll 8
  for (int k = 0; k < 1024; k++) acc += x[k] * pwq[(int64_t)k * 1024 + n];
  qP[(int64_t)r * 1024 + n] = f2bf(acc * 0.125f);
}

// ---------------- pool attention: 1 wave per (b,h), 4 real q-rows ----------------
DEV bool pvalid(int r, int c) {
  if (r == 0) return c < 512;
  if (r == 1) return (c >= 512) && (c < 1024);
  if (r == 2) return (c >= 1024) && (c < 1040);
  return c < 1040;  // GLOBAL row + pad rows
}

__global__ __launch_bounds__(64) void pool_attn_k(const u16* __restrict__ qP,
                                                  const u16* __restrict__ kb,
                                                  const u16* __restrict__ vTb,
                                                  u16* __restrict__ po) {
  const int l = threadIdx.x;
  const int lane16 = l & 15, quad = l >> 4;
  const int bh = blockIdx.x, b = bh >> 4, h = bh & 15;
  __shared__ __align__(16) u16 myp[16 * 32];
  const u16* qp = qP + (int64_t)lane16 * 1024 + h * 64 + quad * 8;
  const bf16x8 a0 = *(const bf16x8*)qp;
  const bf16x8 a1 = *(const bf16x8*)(qp + 32);
  const floatx4 fz = {0.f, 0.f, 0.f, 0.f};
  floatx4 O[4] = {fz, fz, fz, fz};
  float mrow[4] = {-1e30f, -1e30f, -1e30f, -1e30f};
  float lrow[4] = {0.f, 0.f, 0.f, 0.f};
  for (int it = 0; it < 33; ++it) {
    const int c0 = it * 32;
    const u16* kp = kb + ((int64_t)bh * NPAD + c0 + lane16) * 64 + quad * 8;
    bf16x8 b00 = *(const bf16x8*)kp;
    bf16x8 b01 = *(const bf16x8*)(kp + 32);
    bf16x8 b10 = *(const bf16x8*)(kp + 16 * 64);
    bf16x8 b11 = *(const bf16x8*)(kp + 16 * 64 + 32);
    floatx4 s0 = MFMA(a0, b00, fz); s0 = MFMA(a1, b01, s0);
    floatx4 s1 = MFMA(a0, b10, fz); s1 = MFMA(a1, b11, s1);
#pragma unroll
    for (int r = 0; r < 4; r++) {
      if (!pvalid(quad * 4 + r, c0 + lane16)) s0[r] = -1e30f;
      if (!pvalid(quad * 4 + r, c0 + 16 + lane16)) s1[r] = -1e30f;
    }
    float al[4];
#pragma unroll
    for (int r = 0; r < 4; r++) {
      float tm = fmaxf(s0[r], s1[r]);
      tm = fmaxf(tm, __shfl_xor(tm, 1));
      tm = fmaxf(tm, __shfl_xor(tm, 2));
      tm = fmaxf(tm, __shfl_xor(tm, 4));
      tm = fmaxf(tm, __shfl_xor(tm, 8));
      const float mn = fmaxf(mrow[r], tm);
      const float p0 = __expf(s0[r] - mn);
      const float p1 = __expf(s1[r] - mn);
      float ps = p0 + p1;
      ps += __shfl_xor(ps, 1); ps += __shfl_xor(ps, 2);
      ps += __shfl_xor(ps, 4); ps += __shfl_xor(ps, 8);
      const float a_ = __expf(mrow[r] - mn);
      lrow[r] = lrow[r] * a_ + ps;
      mrow[r] = mn;
      al[r] = a_;
      myp[(quad * 4 + r) * 32 + lane16] = f2bf(p0);
      myp[(quad * 4 + r) * 32 + 16 + lane16] = f2bf(p1);
    }
#pragma unroll
    for (int dt = 0; dt < 4; dt++) {
      O[dt][0] *= al[0]; O[dt][1] *= al[1];
      O[dt][2] *= al[2]; O[dt][3] *= al[3];
    }
    const bf16x8 pf = *(const bf16x8*)(myp + lane16 * 32 + quad * 8);
#pragma unroll
    for (int dt = 0; dt < 4; dt++) {
      const u16* vp = vTb + ((int64_t)bh * 64 + dt * 16 + lane16) * NPAD + c0 + quad * 8;
      const bf16x8 bv = *(const bf16x8*)vp;
      O[dt] = MFMA(pf, bv, O[dt]);
    }
  }
  if (quad == 0) {  // rows 0..3 only
#pragma unroll
    for (int dt = 0; dt < 4; dt++)
#pragma unroll
      for (int r = 0; r < 4; r++)
        po[((int64_t)b * 4 + r) * 1024 + h * 64 + dt * 16 + lane16] =
            f2bf(O[dt][r] / lrow[r]);
  }
}

// ---------------- final: out = poolO @ pool_wo + return_tokens ----------------
__global__ __launch_bounds__(256) void fout_k(const u16* __restrict__ po,
                                              const float* __restrict__ pwo,
                                              const float* __restrict__ rtk,
                                              float* __restrict__ out) {
  const int row = blockIdx.y;  // b*4 + r, 0..15
  const int n = blockIdx.x * 256 + threadIdx.x;
  const u16* x = po + (int64_t)row * 1024;
  float acc = 0.f;
#pragma unroll 8
  for (int k = 0; k < 1024; k++) acc += bf2f(x[k]) * pwo[(int64_t)k * 1024 + n];
  out[(int64_t)row * 1024 + n] = acc + rtk[(int64_t)(row & 3) * 1024 + n];
}

// ---------------------------------------------------------------------------
extern "C" void kernel_launch(void* const* d_in, const int* in_sizes, int n_in,
                              void* d_out, int out_size, void* d_ws, size_t ws_size,
                              hipStream_t stream) {
  (void)in_sizes; (void)n_in; (void)out_size; (void)ws_size;
  const float* m0p  = (const float*)d_in[0];
  const float* m1p  = (const float*)d_in[1];
  const float* fus  = (const float*)d_in[2];
  const float* rtk  = (const float*)d_in[3];
  const float* lng  = (const float*)d_in[4];
  const float* wq   = (const float*)d_in[5];
  const float* wkv  = (const float*)d_in[6];
  const float* wo   = (const float*)d_in[7];
  const float* w1   = (const float*)d_in[8];
  const float* w2   = (const float*)d_in[9];
  const float* pwq  = (const float*)d_in[10];
  const float* pwkv = (const float*)d_in[11];
  const float* pwo  = (const float*)d_in[12];
  const float* fg   = (const float*)d_in[13];
  float* out = (float*)d_out;

  char* p = (char*)d_ws;
  auto alloc = [&](size_t bytes) -> char* {
    char* r = p;
    p += (bytes + 255) & ~(size_t)255;
    return r;
  };
  // Total footprint ~63 MB.
  u16* warena = (u16*)alloc((size_t)FF2P * 1024 * 2);       // 11.27 MB, per-GEMM weights
  float* tokens = (float*)alloc((size_t)MREAL * 1024 * 4);  // 17.04 MB
  u16* hbuf  = (u16*)alloc((size_t)MPAD * 1024 * 2);        // 8.65 MB (LN out + attn out)
  u16* qb    = (u16*)alloc((size_t)64 * NPAD * 64 * 2);     // 8.65 MB
  u16* kbuf  = (u16*)alloc((size_t)64 * NPAD * 64 * 2);     // 8.65 MB
  u16* vTbuf = (u16*)alloc((size_t)64 * NPAD * 64 * 2);     // 8.65 MB
  u16* h2buf = qb;  // 23.24 MB alias over qb+kbuf+vTbuf (25.95 MB): dead between
                    // attn read and next layer's Q/KV writes; stale k/vT tail
                    // rows [1040,1056) are masked (-1e30) / multiplied by p=0.
  u16* qP    = (u16*)alloc((size_t)16 * 1024 * 2);
  u16* poolO = (u16*)alloc((size_t)16 * 1024 * 2);

  const dim3 tb(32, 8, 1);
  build_tokens_k<<<dim3(1040, 4), 256, 0, stream>>>(m0p, m1p, fus, tokens);

  for (int lyr = 0; lyr < 4; ++lyr) {
    ln_k<<<MREAL, 256, 0, stream>>>(tokens, lng + lyr * 1024, hbuf);
    // Merged QKV weight: arena rows [0,1024)=wq^T, [1024,3072)=wkv^T
    transpose_cvt<<<dim3(32, 32), tb, 0, stream>>>(
        wq + (int64_t)lyr * 1024 * 1024, warena, 1024, 1024, 1024);
    transpose_cvt<<<dim3(32, 64), tb, 0, stream>>>(
        wkv + (int64_t)lyr * 1024 * 2048, warena + (size_t)1024 * 1024, 1024, 2048, 1024);
    gemm_bt<EPI_QKV><<<dim3(24, 33), 256, 0, stream>>>(
        hbuf, warena, 1024, MREAL, nullptr, qb, kbuf, vTbuf, nullptr);
    attn_k<<<dim3(17, 64), 256, 0, stream>>>(qb, kbuf, vTbuf, hbuf);
    transpose_cvt<<<dim3(32, 32), tb, 0, stream>>>(
        wo + (int64_t)lyr * 1024 * 1024, warena, 1024, 1024, 1024);
    gemm_bt<EPI_TOKADD><<<dim3(8, 33, 2), 256, 0, stream>>>(
        hbuf, warena, 1024, MREAL, tokens, nullptr, nullptr, nullptr, nullptr);
    ln_k<<<MREAL, 256, 0, stream>>>(tokens, lng + lyr * 1024, hbuf);
    transpose_w1<<<dim3(32, 172), tb, 0, stream>>>(
        w1 + (int64_t)lyr * 1024 * 5460, warena);
    gemm_bt<EPI_GG><<<dim3(43, 33), 256, 0, stream>>>(
        hbuf, warena, 1024, MREAL, nullptr, nullptr, nullptr, nullptr, h2buf);
    transpose_cvt<<<dim3(86, 32), tb, 0, stream>>>(
        w2 + (int64_t)lyr * 2730 * 1024, warena, 2730, 1024, FFP);
    gemm_bt<EPI_TOKADD><<<dim3(8, 33, 2), 256, 0, stream>>>(
        h2buf, warena, FFP, MREAL, tokens, nullptr, nullptr, nullptr, nullptr);
  }

  ln_k<<<MREAL, 256, 0, stream>>>(tokens, fg, hbuf);
  transpose_cvt<<<dim3(32, 64), tb, 0, stream>>>(pwkv, warena, 1024, 2048, 1024);
  gemm_bt<EPI_KV><<<dim3(16, 33), 256, 0, stream>>>(
      hbuf, warena, 1024, MREAL, nullptr, nullptr, kbuf, vTbuf, nullptr);
  poolq_k<<<dim3(4, 4), 256, 0, stream>>>(rtk, pwq, qP);
  pool_attn_k<<<64, 64, 0, stream>>>(qP, kbuf, vTbuf, poolO);
  fout_k<<<dim3(4, 16), 256, 0, stream>>>(poolO, pwo, rtk, out);
}

// Round 4
// 1896.044 us; speedup vs baseline: 1.0629x; 1.0629x over previous
//
#include <hip/hip_runtime.h>
#include <stdint.h>

// ---------------------------------------------------------------------------
// Zorro-style multimodal transformer, B=4, N=1040 (512+512+16 fusion), D=1024,
// H=16, DH=64, L=4, FF=2730 gated-GELU; final LN + 4-token masked pool attn.
// bf16 MFMA GEMMs; block-mask flash attention (contiguous col ranges).
// R4: revert R3 band swizzle (latency regression: MfmaUtil 23->9.6%);
//     BK=64 per barrier via two BK=32 LDS tiles (barrier count halved,
//     conflict-free 32-el stride preserved). FF pad 2752->2816 (k%64==0).
// ---------------------------------------------------------------------------

#define DEV __device__ __forceinline__

typedef unsigned short u16;
typedef __attribute__((ext_vector_type(8))) __bf16 bf16x8;
typedef __attribute__((ext_vector_type(4))) float floatx4;

DEV u16 f2bf(float f) {
  union { float f; unsigned u; } v; v.f = f;
  return (u16)((v.u + 0x7fffu + ((v.u >> 16) & 1u)) >> 16);  // RNE
}
DEV float bf2f(u16 s) {
  union { unsigned u; float f; } v; v.u = ((unsigned)s) << 16;
  return v.f;
}

#define MFMA(a, b, c) __builtin_amdgcn_mfma_f32_16x16x32_bf16(a, b, c, 0, 0, 0)

DEV void gld16(const u16* g, u16* l) {
  __builtin_amdgcn_global_load_lds((__attribute__((address_space(1))) void*)g,
                                   (__attribute__((address_space(3))) void*)l,
                                   16, 0, 0);
}

// ---------------- constants ----------------
#define MREAL 4160   /* B*N = 4*1040 */
#define MPAD  4224   /* 33*128 */
#define NPAD  1056   /* 1040 padded to x32 */
#define FFP   2816   /* 2730 padded to x64 (split-K=2 -> 1408 = 22*64) */
#define FF2P  5632

// ---------------- weight conversion ----------------
// out[n*Kstride + k] = (k < Kin) ? bf16(in[k*N + n]) : 0    (B^T bf16 layout)
__global__ __launch_bounds__(256) void transpose_cvt(
    const float* __restrict__ in, u16* __restrict__ out,
    int Kin, int N, int Kstride) {
  __shared__ float tile[32][33];
  const int k0 = blockIdx.x * 32, n0 = blockIdx.y * 32;
  const int tx = threadIdx.x, ty = threadIdx.y;
#pragma unroll
  for (int i = 0; i < 4; i++) {
    int k = k0 + ty + i * 8;
    tile[ty + i * 8][tx] = (k < Kin) ? in[(int64_t)k * N + n0 + tx] : 0.f;
  }
  __syncthreads();
#pragma unroll
  for (int i = 0; i < 4; i++) {
    int n = n0 + ty + i * 8;
    int k = k0 + tx;
    if (k < Kstride) out[(int64_t)n * Kstride + k] = f2bf(tile[tx][ty + i * 8]);
  }
}

// ff_w1 [1024 x 5460] -> w1T [5632 x 1024] bf16 with val/gate 16-col interleave:
// out row r: vi = (r/32)*16 + r%16 ; gate if (r/16)&1 ; src col = gate? 2730+vi : vi
__global__ __launch_bounds__(256) void transpose_w1(
    const float* __restrict__ in, u16* __restrict__ out) {
  __shared__ float tile[32][33];
  const int k0 = blockIdx.x * 32;        // D dim
  const int r0 = blockIdx.y * 32;        // output-row dim
  const int tx = threadIdx.x, ty = threadIdx.y;
  const int vb = (r0 >> 5) << 4;         // = r0/2
  const int vi = vb + (tx & 15);
  const int c = (tx < 16) ? vi : 2730 + vi;
  const bool valid = vi < 2730;
#pragma unroll
  for (int i = 0; i < 4; i++) {
    int k = k0 + ty + i * 8;
    tile[ty + i * 8][tx] = valid ? in[(int64_t)k * 5460 + c] : 0.f;
  }
  __syncthreads();
#pragma unroll
  for (int i = 0; i < 4; i++) {
    int rl = ty + i * 8;
    out[(int64_t)(r0 + rl) * 1024 + k0 + tx] = f2bf(tile[tx][rl]);
  }
}

// ---------------- tokens assembly ----------------
__global__ __launch_bounds__(256) void build_tokens_k(
    const float* __restrict__ m0p, const float* __restrict__ m1p,
    const float* __restrict__ fus, float* __restrict__ tokens) {
  const int n = blockIdx.x, b = blockIdx.y, t = threadIdx.x;
  const float* src = (n < 512) ? m0p + ((int64_t)b * 512 + n) * 1024
                   : (n < 1024) ? m1p + ((int64_t)b * 512 + (n - 512)) * 1024
                                : fus + (int64_t)(n - 1024) * 1024;
  float4 v = ((const float4*)src)[t];
  ((float4*)(tokens + ((int64_t)b * 1040 + n) * 1024))[t] = v;
}

// ---------------- layernorm (f32 in, bf16 out) ----------------
__global__ __launch_bounds__(256) void ln_k(const float* __restrict__ x,
                                            const float* __restrict__ gamma,
                                            u16* __restrict__ out) {
  const int r = blockIdx.x, t = threadIdx.x;
  const float4 v = ((const float4*)(x + (int64_t)r * 1024))[t];
  float s = v.x + v.y + v.z + v.w;
  float q = v.x * v.x + v.y * v.y + v.z * v.z + v.w * v.w;
#pragma unroll
  for (int off = 32; off >= 1; off >>= 1) {
    s += __shfl_xor(s, off);
    q += __shfl_xor(q, off);
  }
  __shared__ float red[8];
  const int w = t >> 6, l = t & 63;
  if (l == 0) { red[w] = s; red[4 + w] = q; }
  __syncthreads();
  s = red[0] + red[1] + red[2] + red[3];
  q = red[4] + red[5] + red[6] + red[7];
  const float mu = s * (1.f / 1024.f);
  const float var = q * (1.f / 1024.f) - mu * mu;
  const float rs = rsqrtf(var + 1e-5f);
  const float4 g = ((const float4*)gamma)[t];
  u16* op = out + (int64_t)r * 1024 + t * 4;
  op[0] = f2bf((v.x - mu) * rs * g.x);
  op[1] = f2bf((v.y - mu) * rs * g.y);
  op[2] = f2bf((v.z - mu) * rs * g.z);
  op[3] = f2bf((v.w - mu) * rs * g.w);
}

// ---------------- MFMA GEMM: C[M,N] = A[M,K](bf16) @ Bt[N,K](bf16) ----------------
enum { EPI_QKV = 0, EPI_KV = 1, EPI_TOKADD = 2, EPI_GG = 3 };

// Kstr = row stride of A and Bt; per-z K-range = Kstr / gridDim.z (mult of 64).
template <int EPI>
__global__ __launch_bounds__(256) void gemm_bt(
    const u16* __restrict__ A, const u16* __restrict__ Bt,
    int Kstr, int Mreal,
    float* __restrict__ tokens, u16* __restrict__ oq, u16* __restrict__ ok,
    u16* __restrict__ ovT, u16* __restrict__ oh2) {
  // Two independent BK=32 tiles per operand (conflict-free 32-el stride),
  // staged together -> one barrier per 64 k-steps.
  __shared__ __align__(16) u16 lA0[128 * 32];
  __shared__ __align__(16) u16 lA1[128 * 32];
  __shared__ __align__(16) u16 lB0[128 * 32];
  __shared__ __align__(16) u16 lB1[128 * 32];
  const int t = threadIdx.x;
  const int w = t >> 6, l = t & 63;
  const int lane16 = l & 15, quad = l >> 4;
  const int m0 = blockIdx.y * 128, n0 = blockIdx.x * 128;
  const int wm = (w >> 1) * 64, wn = (w & 1) * 64;

  const int Klen = Kstr / gridDim.z;
  const int koff = blockIdx.z * Klen;

  const floatx4 fz = {0.f, 0.f, 0.f, 0.f};
  floatx4 acc[4][4];
#pragma unroll
  for (int i = 0; i < 4; i++)
#pragma unroll
    for (int j = 0; j < 4; j++) acc[i][j] = fz;

  const int rowL = t >> 2;
  const int colL = (t & 3) * 8;
  const u16* gA = A + (int64_t)(m0 + rowL) * Kstr + koff + colL;
  const u16* gB = Bt + (int64_t)(n0 + rowL) * Kstr + koff + colL;
  u16* lA0p = lA0 + t * 8;
  u16* lA1p = lA1 + t * 8;
  u16* lB0p = lB0 + t * 8;
  u16* lB1p = lB1 + t * 8;
  const int fo = (wm + lane16) * 32 + quad * 8;
  const int fon = (wn + lane16) * 32 + quad * 8;
  const int64_t rsk = (int64_t)64 * Kstr;

  for (int kt = 0; kt < Klen; kt += 64) {
    gld16(gA + kt, lA0p);
    gld16(gA + kt + rsk, lA0p + 64 * 32);
    gld16(gA + kt + 32, lA1p);
    gld16(gA + kt + 32 + rsk, lA1p + 64 * 32);
    gld16(gB + kt, lB0p);
    gld16(gB + kt + rsk, lB0p + 64 * 32);
    gld16(gB + kt + 32, lB1p);
    gld16(gB + kt + 32 + rsk, lB1p + 64 * 32);
    __syncthreads();
    bf16x8 af[4], bf[4];
#pragma unroll
    for (int i = 0; i < 4; i++) af[i] = *(const bf16x8*)(lA0 + fo + i * 16 * 32);
#pragma unroll
    for (int j = 0; j < 4; j++) bf[j] = *(const bf16x8*)(lB0 + fon + j * 16 * 32);
#pragma unroll
    for (int i = 0; i < 4; i++)
#pragma unroll
      for (int j = 0; j < 4; j++) acc[i][j] = MFMA(af[i], bf[j], acc[i][j]);
#pragma unroll
    for (int i = 0; i < 4; i++) af[i] = *(const bf16x8*)(lA1 + fo + i * 16 * 32);
#pragma unroll
    for (int j = 0; j < 4; j++) bf[j] = *(const bf16x8*)(lB1 + fon + j * 16 * 32);
#pragma unroll
    for (int i = 0; i < 4; i++)
#pragma unroll
      for (int j = 0; j < 4; j++) acc[i][j] = MFMA(af[i], bf[j], acc[i][j]);
    __syncthreads();
  }

  // Epilogues. C-layout: lane holds row = quad*4+reg, col = lane16 within frag.
  if constexpr (EPI == EPI_TOKADD) {
    const bool atomic = gridDim.z > 1;
#pragma unroll
    for (int i = 0; i < 4; i++) {
      const int mb = m0 + wm + i * 16 + quad * 4;
#pragma unroll
      for (int reg = 0; reg < 4; reg++) {
        const int m = mb + reg;
        if (m < Mreal) {
          float* tp = tokens + (int64_t)m * 1024;
#pragma unroll
          for (int j = 0; j < 4; j++) {
            const int n = n0 + wn + j * 16 + lane16;
            if (atomic) atomicAdd(tp + n, acc[i][j][reg]);
            else tp[n] += acc[i][j][reg];
          }
        }
      }
    }
  } else if constexpr (EPI == EPI_QKV) {
    // cols [0,1024): Q (scaled), [1024,2048): K, [2048,3072): V^T
#pragma unroll
    for (int i = 0; i < 4; i++) {
      const int mb = m0 + wm + i * 16 + quad * 4;
#pragma unroll
      for (int reg = 0; reg < 4; reg++) {
        const int m = mb + reg;
        if (m < Mreal) {
          const int b = m / 1040, rb = m % 1040;
#pragma unroll
          for (int j = 0; j < 4; j++) {
            const int n = n0 + wn + j * 16 + lane16;
            const float v = acc[i][j][reg];
            if (n < 1024) {
              const int hd = n >> 6, d = n & 63;
              oq[(((int64_t)b * 16 + hd) * NPAD + rb) * 64 + d] = f2bf(v * 0.125f);
            } else if (n < 2048) {
              const int n2 = n - 1024;
              const int hd = n2 >> 6, d = n2 & 63;
              ok[(((int64_t)b * 16 + hd) * NPAD + rb) * 64 + d] = f2bf(v);
            } else {
              const int n2 = n - 2048;
              const int hd = n2 >> 6, d = n2 & 63;
              ovT[(((int64_t)b * 16 + hd) * 64 + d) * NPAD + rb] = f2bf(v);
            }
          }
        }
      }
    }
  } else if constexpr (EPI == EPI_KV) {
#pragma unroll
    for (int i = 0; i < 4; i++) {
      const int mb = m0 + wm + i * 16 + quad * 4;
#pragma unroll
      for (int reg = 0; reg < 4; reg++) {
        const int m = mb + reg;
        if (m < Mreal) {
          const int b = m / 1040, rb = m % 1040;
#pragma unroll
          for (int j = 0; j < 4; j++) {
            const int n = n0 + wn + j * 16 + lane16;
            const float v = acc[i][j][reg];
            if (n < 1024) {
              const int hd = n >> 6, d = n & 63;
              ok[(((int64_t)b * 16 + hd) * NPAD + rb) * 64 + d] = f2bf(v);
            } else {
              const int n2 = n - 1024;
              const int hd = n2 >> 6, d = n2 & 63;
              ovT[(((int64_t)b * 16 + hd) * 64 + d) * NPAD + rb] = f2bf(v);
            }
          }
        }
      }
    }
  } else {  // EPI_GG: cols are (val,gate) alternating 16-groups
#pragma unroll
    for (int i = 0; i < 4; i++) {
      const int mb = m0 + wm + i * 16 + quad * 4;
#pragma unroll
      for (int reg = 0; reg < 4; reg++) {
        const int m = mb + reg;
        u16* hp = oh2 + (int64_t)m * FFP;
#pragma unroll
        for (int j = 0; j < 4; j += 2) {
          const float val = acc[i][j][reg];
          const float g = acc[i][j + 1][reg];
          const float ge = 0.5f * g * (1.f + erff(g * 0.70710678118654752f));
          const int vi = (((n0 + wn + j * 16) >> 5) << 4) + lane16;
          hp[vi] = f2bf(val * ge);
        }
      }
    }
  }
}

// ---------------- block-mask flash attention ----------------
__global__ __launch_bounds__(256) void attn_k(const u16* __restrict__ qb,
                                              const u16* __restrict__ kb,
                                              const u16* __restrict__ vTb,
                                              u16* __restrict__ ao) {
  const int t = threadIdx.x, w = t >> 6, l = t & 63;
  const int lane16 = l & 15, quad = l >> 4;
  const int bh = blockIdx.y, b = bh >> 4, h = bh & 15;
  const int row0 = blockIdx.x * 64 + w * 16;
  __shared__ __align__(16) u16 lp[4][16 * 32];
  if (row0 >= 1040) return;
  u16* myp = lp[w];
  const int type = (row0 < 512) ? 0 : (row0 < 1024 ? 1 : 2);
  const int cbeg = (type == 1) ? 512 : 0;
  const int cend = (type == 0) ? 512 : (type == 1 ? 1024 : 1040);
  const int niter = (cend - cbeg + 31) >> 5;

  const u16* qp = qb + ((int64_t)bh * NPAD + row0 + lane16) * 64 + quad * 8;
  const bf16x8 a0 = *(const bf16x8*)qp;
  const bf16x8 a1 = *(const bf16x8*)(qp + 32);

  const floatx4 fz = {0.f, 0.f, 0.f, 0.f};
  floatx4 O[4] = {fz, fz, fz, fz};
  float mrow[4] = {-1e30f, -1e30f, -1e30f, -1e30f};
  float lrow[4] = {0.f, 0.f, 0.f, 0.f};

  for (int it = 0; it < niter; ++it) {
    const int c0 = cbeg + it * 32;
    const u16* kp = kb + ((int64_t)bh * NPAD + c0 + lane16) * 64 + quad * 8;
    bf16x8 b00 = *(const bf16x8*)kp;
    bf16x8 b01 = *(const bf16x8*)(kp + 32);
    bf16x8 b10 = *(const bf16x8*)(kp + 16 * 64);
    bf16x8 b11 = *(const bf16x8*)(kp + 16 * 64 + 32);
    floatx4 s0 = MFMA(a0, b00, fz); s0 = MFMA(a1, b01, s0);
    floatx4 s1 = MFMA(a0, b10, fz); s1 = MFMA(a1, b11, s1);
    if (c0 + 32 > cend) {  // fusion tail mask (cols >= cend)
      if (c0 + lane16 >= cend) { s0[0] = s0[1] = s0[2] = s0[3] = -1e30f; }
      if (c0 + 16 + lane16 >= cend) { s1[0] = s1[1] = s1[2] = s1[3] = -1e30f; }
    }
    float al[4];
#pragma unroll
    for (int r = 0; r < 4; r++) {
      float tm = fmaxf(s0[r], s1[r]);
      tm = fmaxf(tm, __shfl_xor(tm, 1));
      tm = fmaxf(tm, __shfl_xor(tm, 2));
      tm = fmaxf(tm, __shfl_xor(tm, 4));
      tm = fmaxf(tm, __shfl_xor(tm, 8));
      const float mn = fmaxf(mrow[r], tm);
      const float p0 = __expf(s0[r] - mn);
      const float p1 = __expf(s1[r] - mn);
      float ps = p0 + p1;
      ps += __shfl_xor(ps, 1); ps += __shfl_xor(ps, 2);
      ps += __shfl_xor(ps, 4); ps += __shfl_xor(ps, 8);
      const float a_ = __expf(mrow[r] - mn);
      lrow[r] = lrow[r] * a_ + ps;
      mrow[r] = mn;
      al[r] = a_;
      myp[(quad * 4 + r) * 32 + lane16] = f2bf(p0);
      myp[(quad * 4 + r) * 32 + 16 + lane16] = f2bf(p1);
    }
#pragma unroll
    for (int dt = 0; dt < 4; dt++) {
      O[dt][0] *= al[0]; O[dt][1] *= al[1];
      O[dt][2] *= al[2]; O[dt][3] *= al[3];
    }
    const bf16x8 pf = *(const bf16x8*)(myp + lane16 * 32 + quad * 8);  // A-layout
#pragma unroll
    for (int dt = 0; dt < 4; dt++) {
      const u16* vp = vTb + ((int64_t)bh * 64 + dt * 16 + lane16) * NPAD + c0 + quad * 8;
      const bf16x8 bv = *(const bf16x8*)vp;
      O[dt] = MFMA(pf, bv, O[dt]);
    }
  }
#pragma unroll
  for (int dt = 0; dt < 4; dt++)
#pragma unroll
    for (int r = 0; r < 4; r++) {
      const int row = row0 + quad * 4 + r;
      ao[((int64_t)b * 1040 + row) * 1024 + h * 64 + dt * 16 + lane16] =
          f2bf(O[dt][r] / lrow[r]);
    }
}

// ---------------- pool q: qP[16,1024] = return_tokens @ pool_wq * 0.125 ----------------
__global__ __launch_bounds__(256) void poolq_k(const float* __restrict__ rtk,
                                               const float* __restrict__ pwq,
                                               u16* __restrict__ qP) {
  const int r = blockIdx.y;
  const int n = blockIdx.x * 256 + threadIdx.x;
  const float* x = rtk + (int64_t)r * 1024;
  float acc = 0.f;
#pragma unroll 8
  for (int k = 0; k < 1024; k++) acc += x[k] * pwq[(int64_t)k * 1024 + n];
  qP[(int64_t)r * 1024 + n] = f2bf(acc * 0.125f);
}

// ---------------- pool attention: 1 wave per (b,h), 4 real q-rows ----------------
DEV bool pvalid(int r, int c) {
  if (r == 0) return c < 512;
  if (r == 1) return (c >= 512) && (c < 1024);
  if (r == 2) return (c >= 1024) && (c < 1040);
  return c < 1040;  // GLOBAL row + pad rows
}

__global__ __launch_bounds__(64) void pool_attn_k(const u16* __restrict__ qP,
                                                  const u16* __restrict__ kb,
                                                  const u16* __restrict__ vTb,
                                                  u16* __restrict__ po) {
  const int l = threadIdx.x;
  const int lane16 = l & 15, quad = l >> 4;
  const int bh = blockIdx.x, b = bh >> 4, h = bh & 15;
  __shared__ __align__(16) u16 myp[16 * 32];
  const u16* qp = qP + (int64_t)lane16 * 1024 + h * 64 + quad * 8;
  const bf16x8 a0 = *(const bf16x8*)qp;
  const bf16x8 a1 = *(const bf16x8*)(qp + 32);
  const floatx4 fz = {0.f, 0.f, 0.f, 0.f};
  floatx4 O[4] = {fz, fz, fz, fz};
  float mrow[4] = {-1e30f, -1e30f, -1e30f, -1e30f};
  float lrow[4] = {0.f, 0.f, 0.f, 0.f};
  for (int it = 0; it < 33; ++it) {
    const int c0 = it * 32;
    const u16* kp = kb + ((int64_t)bh * NPAD + c0 + lane16) * 64 + quad * 8;
    bf16x8 b00 = *(const bf16x8*)kp;
    bf16x8 b01 = *(const bf16x8*)(kp + 32);
    bf16x8 b10 = *(const bf16x8*)(kp + 16 * 64);
    bf16x8 b11 = *(const bf16x8*)(kp + 16 * 64 + 32);
    floatx4 s0 = MFMA(a0, b00, fz); s0 = MFMA(a1, b01, s0);
    floatx4 s1 = MFMA(a0, b10, fz); s1 = MFMA(a1, b11, s1);
#pragma unroll
    for (int r = 0; r < 4; r++) {
      if (!pvalid(quad * 4 + r, c0 + lane16)) s0[r] = -1e30f;
      if (!pvalid(quad * 4 + r, c0 + 16 + lane16)) s1[r] = -1e30f;
    }
    float al[4];
#pragma unroll
    for (int r = 0; r < 4; r++) {
      float tm = fmaxf(s0[r], s1[r]);
      tm = fmaxf(tm, __shfl_xor(tm, 1));
      tm = fmaxf(tm, __shfl_xor(tm, 2));
      tm = fmaxf(tm, __shfl_xor(tm, 4));
      tm = fmaxf(tm, __shfl_xor(tm, 8));
      const float mn = fmaxf(mrow[r], tm);
      const float p0 = __expf(s0[r] - mn);
      const float p1 = __expf(s1[r] - mn);
      float ps = p0 + p1;
      ps += __shfl_xor(ps, 1); ps += __shfl_xor(ps, 2);
      ps += __shfl_xor(ps, 4); ps += __shfl_xor(ps, 8);
      const float a_ = __expf(mrow[r] - mn);
      lrow[r] = lrow[r] * a_ + ps;
      mrow[r] = mn;
      al[r] = a_;
      myp[(quad * 4 + r) * 32 + lane16] = f2bf(p0);
      myp[(quad * 4 + r) * 32 + 16 + lane16] = f2bf(p1);
    }
#pragma unroll
    for (int dt = 0; dt < 4; dt++) {
      O[dt][0] *= al[0]; O[dt][1] *= al[1];
      O[dt][2] *= al[2]; O[dt][3] *= al[3];
    }
    const bf16x8 pf = *(const bf16x8*)(myp + lane16 * 32 + quad * 8);
#pragma unroll
    for (int dt = 0; dt < 4; dt++) {
      const u16* vp = vTb + ((int64_t)bh * 64 + dt * 16 + lane16) * NPAD + c0 + quad * 8;
      const bf16x8 bv = *(const bf16x8*)vp;
      O[dt] = MFMA(pf, bv, O[dt]);
    }
  }
  if (quad == 0) {  // rows 0..3 only
#pragma unroll
    for (int dt = 0; dt < 4; dt++)
#pragma unroll
      for (int r = 0; r < 4; r++)
        po[((int64_t)b * 4 + r) * 1024 + h * 64 + dt * 16 + lane16] =
            f2bf(O[dt][r] / lrow[r]);
  }
}

// ---------------- final: out = poolO @ pool_wo + return_tokens ----------------
__global__ __launch_bounds__(256) void fout_k(const u16* __restrict__ po,
                                              const float* __restrict__ pwo,
                                              const float* __restrict__ rtk,
                                              float* __restrict__ out) {
  const int row = blockIdx.y;  // b*4 + r, 0..15
  const int n = blockIdx.x * 256 + threadIdx.x;
  const u16* x = po + (int64_t)row * 1024;
  float acc = 0.f;
#pragma unroll 8
  for (int k = 0; k < 1024; k++) acc += bf2f(x[k]) * pwo[(int64_t)k * 1024 + n];
  out[(int64_t)row * 1024 + n] = acc + rtk[(int64_t)(row & 3) * 1024 + n];
}

// ---------------------------------------------------------------------------
extern "C" void kernel_launch(void* const* d_in, const int* in_sizes, int n_in,
                              void* d_out, int out_size, void* d_ws, size_t ws_size,
                              hipStream_t stream) {
  (void)in_sizes; (void)n_in; (void)out_size; (void)ws_size;
  const float* m0p  = (const float*)d_in[0];
  const float* m1p  = (const float*)d_in[1];
  const float* fus  = (const float*)d_in[2];
  const float* rtk  = (const float*)d_in[3];
  const float* lng  = (const float*)d_in[4];
  const float* wq   = (const float*)d_in[5];
  const float* wkv  = (const float*)d_in[6];
  const float* wo   = (const float*)d_in[7];
  const float* w1   = (const float*)d_in[8];
  const float* w2   = (const float*)d_in[9];
  const float* pwq  = (const float*)d_in[10];
  const float* pwkv = (const float*)d_in[11];
  const float* pwo  = (const float*)d_in[12];
  const float* fg   = (const float*)d_in[13];
  float* out = (float*)d_out;

  char* p = (char*)d_ws;
  auto alloc = [&](size_t bytes) -> char* {
    char* r = p;
    p += (bytes + 255) & ~(size_t)255;
    return r;
  };
  // Total footprint ~64 MB.
  u16* warena = (u16*)alloc((size_t)FF2P * 1024 * 2);       // 11.5 MB, per-GEMM weights
  float* tokens = (float*)alloc((size_t)MREAL * 1024 * 4);  // 17.04 MB
  u16* hbuf  = (u16*)alloc((size_t)MPAD * 1024 * 2);        // 8.65 MB (LN out + attn out)
  u16* qb    = (u16*)alloc((size_t)64 * NPAD * 64 * 2);     // 8.65 MB
  u16* kbuf  = (u16*)alloc((size_t)64 * NPAD * 64 * 2);     // 8.65 MB
  u16* vTbuf = (u16*)alloc((size_t)64 * NPAD * 64 * 2);     // 8.65 MB
  u16* h2buf = qb;  // 23.8 MB alias over qb+kbuf+vTbuf (25.95 MB): dead between
                    // attn read and next layer's Q/KV writes; stale k/vT tail
                    // rows [1040,1056) are masked (-1e30) / multiplied by p=0.
  u16* qP    = (u16*)alloc((size_t)16 * 1024 * 2);
  u16* poolO = (u16*)alloc((size_t)16 * 1024 * 2);

  const dim3 tb(32, 8, 1);
  build_tokens_k<<<dim3(1040, 4), 256, 0, stream>>>(m0p, m1p, fus, tokens);

  for (int lyr = 0; lyr < 4; ++lyr) {
    ln_k<<<MREAL, 256, 0, stream>>>(tokens, lng + lyr * 1024, hbuf);
    // Merged QKV weight: arena rows [0,1024)=wq^T, [1024,3072)=wkv^T
    transpose_cvt<<<dim3(32, 32), tb, 0, stream>>>(
        wq + (int64_t)lyr * 1024 * 1024, warena, 1024, 1024, 1024);
    transpose_cvt<<<dim3(32, 64), tb, 0, stream>>>(
        wkv + (int64_t)lyr * 1024 * 2048, warena + (size_t)1024 * 1024, 1024, 2048, 1024);
    gemm_bt<EPI_QKV><<<dim3(24, 33), 256, 0, stream>>>(
        hbuf, warena, 1024, MREAL, nullptr, qb, kbuf, vTbuf, nullptr);
    attn_k<<<dim3(17, 64), 256, 0, stream>>>(qb, kbuf, vTbuf, hbuf);
    transpose_cvt<<<dim3(32, 32), tb, 0, stream>>>(
        wo + (int64_t)lyr * 1024 * 1024, warena, 1024, 1024, 1024);
    gemm_bt<EPI_TOKADD><<<dim3(8, 33, 2), 256, 0, stream>>>(
        hbuf, warena, 1024, MREAL, tokens, nullptr, nullptr, nullptr, nullptr);
    ln_k<<<MREAL, 256, 0, stream>>>(tokens, lng + lyr * 1024, hbuf);
    transpose_w1<<<dim3(32, FF2P / 32), tb, 0, stream>>>(
        w1 + (int64_t)lyr * 1024 * 5460, warena);
    gemm_bt<EPI_GG><<<dim3(FF2P / 128, 33), 256, 0, stream>>>(
        hbuf, warena, 1024, MREAL, nullptr, nullptr, nullptr, nullptr, h2buf);
    transpose_cvt<<<dim3(FFP / 32, 32), tb, 0, stream>>>(
        w2 + (int64_t)lyr * 2730 * 1024, warena, 2730, 1024, FFP);
    gemm_bt<EPI_TOKADD><<<dim3(8, 33, 2), 256, 0, stream>>>(
        h2buf, warena, FFP, MREAL, tokens, nullptr, nullptr, nullptr, nullptr);
  }

  ln_k<<<MREAL, 256, 0, stream>>>(tokens, fg, hbuf);
  transpose_cvt<<<dim3(32, 64), tb, 0, stream>>>(pwkv, warena, 1024, 2048, 1024);
  gemm_bt<EPI_KV><<<dim3(16, 33), 256, 0, stream>>>(
      hbuf, warena, 1024, MREAL, nullptr, nullptr, kbuf, vTbuf, nullptr);
  poolq_k<<<dim3(4, 4), 256, 0, stream>>>(rtk, pwq, qP);
  pool_attn_k<<<64, 64, 0, stream>>>(qP, kbuf, vTbuf, poolO);
  fout_k<<<dim3(4, 16), 256, 0, stream>>>(poolO, pwo, rtk, out);
}